// Round 7
// baseline (187.081 us; speedup 1.0000x reference)
//
#include <hip/hip_runtime.h>
#include <hip/hip_bf16.h>

// Voxelization scatter-mean, round 7:
//   1) vox_init: blocks 0-31 build exact per-(batch,half) histograms in LDS
//      (21888 bins, 87.5 KB) and plain-store to cnt2[2][B][R]; blocks 32-255
//      grid-stride-zero the bf16 acc. One dispatch replaces the memset AND
//      removes all 262K cnt line-RMWs from the scatter.
//   2) vox_scatter_pk: LDS-transpose 64pt x 64ch feat tiles; per point one
//      half-wave (32-lane) global_atomic_pk_add_bf16 row-add (2 lines/point).
//   3) vox_finish_pk2: cnt-guarded bf16 row read (cnt = cnt2[0]+cnt2[1]),
//      normalize, LDS transpose, coalesced fp32 [B][C][R] writes.
// Fallback (small ws): round-4 fp32-atomic path.

#define BB 16
#define CC 64
#define NN 16384
#define XX 38
#define YY 24
#define ZZ 24
#define RR (XX * YY * ZZ)   // 21888
#define NTILES (RR / 64)    // 342
#define ACC_U4 2801664      // (BB*RR*64*2) / 16 uint4 elements (44.8 MB)
#define ZBLK 224            // zeroing blocks in vox_init (grid = 32 + ZBLK)

__device__ __forceinline__ int voxel_id(const float* __restrict__ coords, int t) {
    float cx = coords[t * 3 + 0];
    float cy = coords[t * 3 + 1];
    float cz = coords[t * 3 + 2];
    // Match reference IEEE ops: floor(c / voxel_size) - min_voxel_coord
    int ix = (int)(floorf(cx / 0.3f) + 19.0f);
    int iy = (int)(floorf(cy / 0.3f) + 12.0f);
    int iz = (int)(floorf(cz / 0.2f) + 12.0f);
    bool valid = (ix >= 0) & (ix < XX) & (iy >= 0) & (iy < YY) &
                 (iz >= 0) & (iz < ZZ);
    return valid ? (ix * (YY * ZZ) + iy * ZZ + iz) : RR;
}

__device__ __forceinline__ unsigned int pack2_bf16_rne(float a, float b) {
    unsigned int ua = __float_as_uint(a), ub = __float_as_uint(b);
    ua = (ua + 0x7fffu + ((ua >> 16) & 1u)) >> 16;   // round-nearest-even
    ub = (ub + 0x7fffu + ((ub >> 16) & 1u)) >> 16;
    return ua | (ub << 16);
}

// Blocks 0..31: LDS histogram for (batch b = bx>>1, half = bx&1), 8192 points
// each, plain-stored to cnt2[(half*BB+b)*RR + *]. Blocks 32..255: zero acc.
__global__ void __launch_bounds__(1024)
vox_init(const float* __restrict__ coords,
         uint4* __restrict__ acc_vec,
         int* __restrict__ cnt2) {
    __shared__ int h[RR];            // 87552 B
    int bx = blockIdx.x, tid = threadIdx.x;

    if (bx < 32) {
        int b = bx >> 1, half = bx & 1;
        for (int i = tid; i < RR; i += 1024) h[i] = 0;
        __syncthreads();
        int base = b * NN + half * (NN / 2);
#pragma unroll
        for (int i = 0; i < 8; ++i) {
            int v = voxel_id(coords, base + i * 1024 + tid);
            if (v < RR) atomicAdd(&h[v], 1);
        }
        __syncthreads();
        int* dst = cnt2 + (size_t)(half * BB + b) * RR;
        for (int i = tid; i < RR; i += 1024) dst[i] = h[i];   // coalesced, exact
    } else {
        int zb = bx - 32;            // 0..ZBLK-1
        uint4 z = make_uint4(0, 0, 0, 0);
        for (int i = zb * 1024 + tid; i < ACC_U4; i += ZBLK * 1024)
            acc_vec[i] = z;
    }
}

// Block = 64 points x 64 channels (4 waves). Coalesced feat read, LDS
// transpose; per point a 32-lane pk-bf16 atomic row-add (2 lines, no cnt).
__global__ void vox_scatter_pk(const float* __restrict__ feat,
                               const float* __restrict__ coords,
                               unsigned short* __restrict__ acc) {  // bf16 [B][R][64]
    __shared__ float lt[64][66];     // stride 66 keeps float2 reads 8B-aligned
    __shared__ int vv[64];
    int blk = blockIdx.x;            // B * (N/64) = 4096
    int b = blk >> 8;
    int n0 = (blk & 255) * 64;
    int tid = threadIdx.x;
    int lane = tid & 63, w = tid >> 6;

    if (tid < 64) {
        vv[tid] = voxel_id(coords, b * NN + n0 + tid);
    }

    const float* fb = feat + (size_t)b * CC * NN;
#pragma unroll
    for (int it = 0; it < 16; ++it) {
        int c = it * 4 + w;
        lt[lane][c] = fb[(size_t)c * NN + n0 + lane];   // 256B coalesced
    }
    __syncthreads();

    int half = lane >> 5, l = lane & 31;   // half-wave handles one point
#pragma unroll
    for (int i = 0; i < 8; ++i) {
        int p = w * 16 + i * 2 + half;
        int v = vv[p];
        if (v < RR) {
            float2 ab = *(const float2*)&lt[p][2 * l];
            unsigned int pk = pack2_bf16_rne(ab.x, ab.y);
            unsigned long long addr = (unsigned long long)acc +
                ((size_t)b * RR + v) * 128ull + 4ull * l;   // 32 lanes: 128B row
            asm volatile("global_atomic_pk_add_bf16 %0, %1, off"
                         :: "v"(addr), "v"(pk) : "memory");
        }
    }
}

// Block = 64 voxels x 64 channels. cnt-guarded bf16 row read, normalize,
// LDS transpose, coalesced fp32 [B][C][R] writes.
__global__ void vox_finish_pk2(const unsigned short* __restrict__ acc,
                               const int* __restrict__ cnt2,
                               float* __restrict__ out) {
    __shared__ float lt[64][65];
    int blk = blockIdx.x;            // B * NTILES = 5472
    int b = blk / NTILES;
    int r0 = (blk % NTILES) * 64;
    int tid = threadIdx.x;
    int lane = tid & 63, w = tid >> 6;

#pragma unroll
    for (int i = 0; i < 16; ++i) {
        int rl = w * 16 + i;
        int r = r0 + rl;
        int c_ = cnt2[(size_t)b * RR + r] +
                 cnt2[(size_t)(BB + b) * RR + r];        // wave-scalar pair
        float val = 0.0f;
        if (c_ > 0) {
            unsigned short hv = acc[((size_t)b * RR + r) * 64 + lane]; // 128B row
            val = __uint_as_float((unsigned int)hv << 16) / (float)c_;
        }
        lt[rl][lane] = val;
    }
    __syncthreads();

    float* ob = out + (size_t)b * CC * RR;
#pragma unroll
    for (int it = 0; it < 16; ++it) {
        int idx = it * 256 + tid;
        int c = idx >> 6, rr = idx & 63;                 // c wave-uniform
        ob[(size_t)c * RR + r0 + rr] = lt[rr][c];        // 256B coalesced
    }
}

// ---------------- fallback: round-4 fp32-atomic path ----------------

__global__ void vox_scatter_t(const float* __restrict__ feat,
                              const float* __restrict__ coords,
                              float* __restrict__ acc,
                              int* __restrict__ cnt) {
    __shared__ float lt[64][65];
    __shared__ int vv[64];
    int blk = blockIdx.x;
    int b = blk >> 8;
    int n0 = (blk & 255) * 64;
    int tid = threadIdx.x;
    int lane = tid & 63, w = tid >> 6;
    if (tid < 64) {
        int v = voxel_id(coords, b * NN + n0 + tid);
        vv[tid] = v;
        if (v < RR) atomicAdd(&cnt[b * RR + v], 1);
    }
    const float* fb = feat + (size_t)b * CC * NN;
#pragma unroll
    for (int it = 0; it < 16; ++it) {
        int c = it * 4 + w;
        lt[lane][c] = fb[(size_t)c * NN + n0 + lane];
    }
    __syncthreads();
#pragma unroll
    for (int i = 0; i < 16; ++i) {
        int p = w * 16 + i;
        int v = vv[p];
        if (v < RR) atomicAdd(&acc[((size_t)b * RR + v) * CC + lane], lt[p][lane]);
    }
}

__global__ void vox_finish(const float* __restrict__ acc,
                           const int* __restrict__ cnt,
                           float* __restrict__ out) {
    __shared__ float lt[64][65];
    int blk = blockIdx.x;
    int b = blk / NTILES;
    int r0 = (blk % NTILES) * 64;
    int tid = threadIdx.x;
    int lane = tid & 63, w = tid >> 6;
#pragma unroll
    for (int i = 0; i < 16; ++i) {
        int rl = w * 16 + i;
        int r = r0 + rl;
        int c_ = cnt[b * RR + r];
        float val = 0.0f;
        if (c_ > 0) val = acc[((size_t)b * RR + r) * CC + lane] / (float)c_;
        lt[rl][lane] = val;
    }
    __syncthreads();
    float* ob = out + (size_t)b * CC * RR;
#pragma unroll
    for (int it = 0; it < 16; ++it) {
        int idx = it * 256 + tid;
        int c = idx >> 6, rr = idx & 63;
        ob[(size_t)c * RR + r0 + rr] = lt[rr][c];
    }
}

extern "C" void kernel_launch(void* const* d_in, const int* in_sizes, int n_in,
                              void* d_out, int out_size, void* d_ws, size_t ws_size,
                              hipStream_t stream) {
    const float* feat   = (const float*)d_in[0];   // [B, C, N]
    const float* coords = (const float*)d_in[1];   // [B, N, 3]
    float* out = (float*)d_out;                    // [B, C, X, Y, Z]

    size_t acc_bytes = (size_t)ACC_U4 * 16;                  // 44.8 MB bf16
    size_t cnt2_bytes = 2ull * BB * RR * sizeof(int);        // 2.8 MB
    size_t need_pk = acc_bytes + cnt2_bytes;                 // 47.6 MB

    if (ws_size >= need_pk) {
        unsigned short* acc = (unsigned short*)d_ws;         // bf16 [B][R][64]
        int* cnt2 = (int*)((char*)d_ws + acc_bytes);         // [2][B][R]

        vox_init<<<32 + ZBLK, 1024, 0, stream>>>(coords, (uint4*)d_ws, cnt2);
        vox_scatter_pk<<<BB * (NN / 64), 256, 0, stream>>>(feat, coords, acc);
        vox_finish_pk2<<<BB * NTILES, 256, 0, stream>>>(acc, cnt2, out);
        return;
    }

    size_t acc_elems = (size_t)BB * RR * CC;
    size_t need_f32 = (acc_elems + (size_t)BB * RR) * 4;     // ~91.1 MB
    if (ws_size >= need_f32) {
        float* acc = (float*)d_ws;
        int* cnt = (int*)(acc + acc_elems);
        hipMemsetAsync(d_ws, 0, need_f32, stream);
        vox_scatter_t<<<BB * (NN / 64), 256, 0, stream>>>(feat, coords, acc, cnt);
        vox_finish<<<BB * NTILES, 256, 0, stream>>>(acc, cnt, out);
    }
}